// Round 2
// 431.167 us; speedup vs baseline: 1.0747x; 1.0747x over previous
//
#include <hip/hip_runtime.h>
#include <stdint.h>
#include <stddef.h>

// Problem constants
#define BB 4
#define CC 256
#define NH 8
#define DH 32
#define NN 2304      // 48*48
#define O3 768
#define HID 256
#define QK_SCALE 0.17677669529663687f  // 32^-0.5
#define LOG2E 1.44269504f

typedef __attribute__((ext_vector_type(8))) short short8;
typedef __attribute__((ext_vector_type(4))) float float4v;

__device__ __forceinline__ unsigned short f2bf(float f) {
    union { float f; uint32_t u; } v; v.f = f;
    uint32_t u = v.u;
    return (unsigned short)((u + 0x7FFFu + ((u >> 16) & 1u)) >> 16);   // RNE
}
__device__ __forceinline__ float bf2f(unsigned short s) {
    union { uint32_t u; float f; } v; v.u = ((uint32_t)s) << 16;
    return v.f;
}

// ---------------------------------------------------------------------------
// K0: prep = transpose-cast x -> xT bf16  (blocks 0..2303)
//          + cast w_qkv hi/lo, w_out      (blocks 2304..3071)
// ---------------------------------------------------------------------------
__global__ __launch_bounds__(256) void prep_kernel(const float* __restrict__ x,
                                                   const float* __restrict__ wqkv,
                                                   const float* __restrict__ wout,
                                                   unsigned short* __restrict__ xT,
                                                   unsigned short* __restrict__ whi,
                                                   unsigned short* __restrict__ wlo,
                                                   unsigned short* __restrict__ wob) {
    const int bid = blockIdx.x;
    const int t = threadIdx.x;
    if (bid < 2304) {      // transpose 32x32 tile of x
        const int n0 = (bid % 72) * 32, c0 = ((bid / 72) % 8) * 32, b = bid / 576;
        __shared__ float ls[32][33];
        {
            int c = t >> 3, nc = (t & 7) * 4;
            float4 v4 = *(const float4*)(x + ((size_t)b * CC + c0 + c) * NN + n0 + nc);
            ls[c][nc] = v4.x; ls[c][nc + 1] = v4.y; ls[c][nc + 2] = v4.z; ls[c][nc + 3] = v4.w;
        }
        __syncthreads();
        {
            int n = t >> 3, cl = (t & 7) * 4;
            uint32_t p0 = (uint32_t)f2bf(ls[cl + 0][n]) | ((uint32_t)f2bf(ls[cl + 1][n]) << 16);
            uint32_t p1 = (uint32_t)f2bf(ls[cl + 2][n]) | ((uint32_t)f2bf(ls[cl + 3][n]) << 16);
            uint32_t* dst = (uint32_t*)(xT + ((size_t)b * NN + n0 + n) * CC + c0 + cl);
            dst[0] = p0; dst[1] = p1;
        }
    } else {               // weight casts
        int i = (bid - 2304) * 256 + t;
        float wv = wqkv[i];
        unsigned short hi = f2bf(wv);
        whi[i] = hi;
        wlo[i] = f2bf(wv - bf2f(hi));
        if (i < HID * HID) wob[i] = f2bf(wout[i]);
    }
}

// ---------------------------------------------------------------------------
// K1: fused QKV projection, bf16 MFMA, writes q/k/v directly in final layouts.
//   q,k bf16 [b][h][n][32] (q scaled by QK_SCALE*LOG2E), v bf16 [b][h][32][n]
// ---------------------------------------------------------------------------
__global__ __launch_bounds__(256) void qkv_gemm_bf16(const unsigned short* __restrict__ xT,
                                                     const unsigned short* __restrict__ whi,
                                                     const unsigned short* __restrict__ wlo,
                                                     unsigned short* __restrict__ q,
                                                     unsigned short* __restrict__ k,
                                                     unsigned short* __restrict__ v) {
    const int og = blockIdx.x;
    const int n0 = blockIdx.y * 64;
    const int b  = blockIdx.z;
    const int t = threadIdx.x;
    const int w = t >> 6, lane = t & 63, l15 = lane & 15, quad = lane >> 4;
    const unsigned short* xb = xT + (size_t)b * NN * CC;

    float4v acc[4] = {{0.f,0.f,0.f,0.f},{0.f,0.f,0.f,0.f},
                      {0.f,0.f,0.f,0.f},{0.f,0.f,0.f,0.f}};

    if (og < 8) {   // ---- qk mode: A = xT rows n, B = w rows o ----
        const int o0 = og * 64;
        const unsigned short* ap = xb + (size_t)(n0 + w * 16 + l15) * CC + quad * 8;
        #pragma unroll
        for (int c0 = 0; c0 < CC; c0 += 32) {
            short8 af = *(const short8*)(ap + c0);
            #pragma unroll
            for (int jj = 0; jj < 4; ++jj) {
                const size_t wo = (size_t)(o0 + jj * 16 + l15) * CC + c0 + quad * 8;
                short8 bh = *(const short8*)(whi + wo);
                short8 bl = *(const short8*)(wlo + wo);
                acc[jj] = __builtin_amdgcn_mfma_f32_16x16x32_bf16(af, bh, acc[jj], 0, 0, 0);
                acc[jj] = __builtin_amdgcn_mfma_f32_16x16x32_bf16(af, bl, acc[jj], 0, 0, 0);
            }
        }
        #pragma unroll
        for (int jj = 0; jj < 4; ++jj) {
            const int o = o0 + jj * 16 + l15;
            const int which = o >> 8;            // 0=q 1=k
            const int h = (o >> 5) & 7, d = o & 31;
            unsigned short* dst = which ? k : q;
            const float sc = which ? 1.0f : QK_SCALE * LOG2E;
            #pragma unroll
            for (int r = 0; r < 4; ++r) {
                const int n = n0 + w * 16 + quad * 4 + r;
                dst[(((size_t)b * NH + h) * NN + n) * DH + d] = f2bf(acc[jj][r] * sc);
            }
        }
    } else {        // ---- v mode: A = w rows o, B = xT rows n ----
        const int o0 = 512 + (og - 8) * 64;
        const size_t wr = (size_t)(o0 + w * 16 + l15) * CC + quad * 8;
        #pragma unroll
        for (int c0 = 0; c0 < CC; c0 += 32) {
            short8 ah = *(const short8*)(whi + wr + c0);
            short8 al = *(const short8*)(wlo + wr + c0);
            #pragma unroll
            for (int jj = 0; jj < 4; ++jj) {
                short8 bf = *(const short8*)(xb + (size_t)(n0 + jj * 16 + l15) * CC + c0 + quad * 8);
                acc[jj] = __builtin_amdgcn_mfma_f32_16x16x32_bf16(ah, bf, acc[jj], 0, 0, 0);
                acc[jj] = __builtin_amdgcn_mfma_f32_16x16x32_bf16(al, bf, acc[jj], 0, 0, 0);
            }
        }
        #pragma unroll
        for (int r = 0; r < 4; ++r) {
            const int o = o0 + w * 16 + quad * 4 + r;
            const int h = (o >> 5) & 7, d = o & 31;
            #pragma unroll
            for (int jj = 0; jj < 4; ++jj) {
                const int n = n0 + jj * 16 + l15;
                v[(((size_t)b * NH + h) * DH + d) * NN + n] = f2bf(acc[jj][r]);
            }
        }
    }
}

// ---------------------------------------------------------------------------
// K2: fused attention, BATCH-FUSED: one block = 4 waves = 4 batches sharing
// one (head, i-tile). pos_bias is batch-independent, so the 16x128 bias tile
// is staged ONCE per block into LDS (coalesced float4 loads, premultiplied by
// LOG2E, bf16, pad-132 stride -> conflict-free reads) instead of 32 per-lane
// global scalar loads per wave-iteration. Staging is double-buffered with
// issue-early/write-late (T14): next tile's global loads issue at the top of
// the iteration, the LDS write + single barrier at the bottom, so HBM latency
// hides under QK/exp/PV. Global bias demand drops 4x (680 MB -> 170 MB,
// read exactly once). Wave count unchanged (4608); per-wave verified math
// unchanged (no max-tracking, wave-private ps, RNE f2bf, fp32 row sums).
// grid (NN/16, NH), block 256.
// ---------------------------------------------------------------------------
__global__ __launch_bounds__(256) void attn_kernel(const unsigned short* __restrict__ qg,
                                                   const unsigned short* __restrict__ kg,
                                                   const unsigned short* __restrict__ vg,
                                                   const float* __restrict__ bias,
                                                   unsigned short* __restrict__ ao) {
    const int i0   = blockIdx.x * 16;
    const int h    = blockIdx.y;
    const int t    = threadIdx.x;
    const int b    = t >> 6;            // wave index = batch index (BB==4)
    const int lane = t & 63;
    const int l15  = lane & 15;
    const int quad = lane >> 4;

    __shared__ __align__(16) unsigned short bls[2][16][132];  // bias dbuf, 8.4 KB
    __shared__ __align__(16) unsigned short ps[BB][16][136];  // per-wave P, 17.4 KB

    const size_t bh = (size_t)b * NH + h;
    const unsigned short* qp = qg + bh * NN * DH;
    const unsigned short* kp = kg + bh * NN * DH;
    const unsigned short* vp = vg + bh * DH * NN;

    short8 qf = *(const short8*)(qp + (size_t)(i0 + l15) * DH + quad * 8);

    float4v oa0 = {0.f, 0.f, 0.f, 0.f};
    float4v oa1 = {0.f, 0.f, 0.f, 0.f};
    float4v zero = {0.f, 0.f, 0.f, 0.f};
    float l_r[4] = {0.f, 0.f, 0.f, 0.f};

    // cooperative bias staging: thread t covers rows {t>>5, (t>>5)+8},
    // cols (t&31)*4 .. +3 of the 16x128 tile (fully coalesced 512B/row/wave)
    const float* bsrc = bias + ((size_t)h * NN + i0) * NN;
    const int srow = t >> 5;
    const int scol = (t & 31) * 4;

    // prologue: stage tile jt=0
    {
        float4 a = *(const float4*)(bsrc + (size_t)srow * NN + scol);
        float4 c = *(const float4*)(bsrc + (size_t)(srow + 8) * NN + scol);
        uint32_t* d0 = (uint32_t*)&bls[0][srow][scol];
        d0[0] = (uint32_t)f2bf(a.x * LOG2E) | ((uint32_t)f2bf(a.y * LOG2E) << 16);
        d0[1] = (uint32_t)f2bf(a.z * LOG2E) | ((uint32_t)f2bf(a.w * LOG2E) << 16);
        uint32_t* d1 = (uint32_t*)&bls[0][srow + 8][scol];
        d1[0] = (uint32_t)f2bf(c.x * LOG2E) | ((uint32_t)f2bf(c.y * LOG2E) << 16);
        d1[1] = (uint32_t)f2bf(c.z * LOG2E) | ((uint32_t)f2bf(c.w * LOG2E) << 16);
    }
    __syncthreads();

    int cur = 0;
    for (int jt = 0; jt < NN; jt += 128) {
        const int jtn = jt + 128;
        const bool have = (jtn < NN);          // uniform across block
        float4 a, c;
        if (have) {                            // issue next-tile loads EARLY
            a = *(const float4*)(bsrc + (size_t)srow * NN + jtn + scol);
            c = *(const float4*)(bsrc + (size_t)(srow + 8) * NN + jtn + scol);
        }

        // preload this tile's bias fragment from LDS (C-layout, 2-way max
        // bank aliasing with the 132-short row stride -> free)
        float bc[4][8];
        #pragma unroll
        for (int r = 0; r < 4; ++r)
            #pragma unroll
            for (int jj = 0; jj < 8; ++jj)
                bc[r][jj] = bf2f(bls[cur][quad * 4 + r][jj * 16 + l15]);

        // S = Q K^T : 8 MFMAs (q pre-scaled by SCALE*LOG2E)
        float4v s[8];
        #pragma unroll
        for (int jj = 0; jj < 8; ++jj) {
            short8 kf = *(const short8*)(kp + (size_t)(jt + jj * 16 + l15) * DH + quad * 8);
            s[jj] = __builtin_amdgcn_mfma_f32_16x16x32_bf16(qf, kf, zero, 0, 0, 0);
        }

        // p = exp2(s + bias*log2e); per-lane partial row sums only
        #pragma unroll
        for (int r = 0; r < 4; ++r) {
            const int row = quad * 4 + r;
            #pragma unroll
            for (int jj = 0; jj < 8; ++jj) {
                float p = exp2f(s[jj][r] + bc[r][jj]);
                l_r[r] += p;
                ps[b][row][jj * 16 + l15] = f2bf(p);
            }
        }

        // O += P x V  (ps wave-private: same-wave DS ordering, no barrier)
        #pragma unroll
        for (int cc = 0; cc < 4; ++cc) {
            short8 pa = *(const short8*)&ps[b][l15][cc * 32 + quad * 8];
            short8 v0 = *(const short8*)(vp + (size_t)l15 * NN        + jt + cc * 32 + quad * 8);
            short8 v1 = *(const short8*)(vp + (size_t)(l15 + 16) * NN + jt + cc * 32 + quad * 8);
            oa0 = __builtin_amdgcn_mfma_f32_16x16x32_bf16(pa, v0, oa0, 0, 0, 0);
            oa1 = __builtin_amdgcn_mfma_f32_16x16x32_bf16(pa, v1, oa1, 0, 0, 0);
        }

        // write-LATE: convert + store next bias tile, then the iteration's
        // single barrier. Reads of bls[cur] (iter i) and writes of the same
        // buffer (iter i+1) are separated by this barrier.
        if (have) {
            const int nxt = cur ^ 1;
            uint32_t* d0 = (uint32_t*)&bls[nxt][srow][scol];
            d0[0] = (uint32_t)f2bf(a.x * LOG2E) | ((uint32_t)f2bf(a.y * LOG2E) << 16);
            d0[1] = (uint32_t)f2bf(a.z * LOG2E) | ((uint32_t)f2bf(a.w * LOG2E) << 16);
            uint32_t* d1 = (uint32_t*)&bls[nxt][srow + 8][scol];
            d1[0] = (uint32_t)f2bf(c.x * LOG2E) | ((uint32_t)f2bf(c.y * LOG2E) << 16);
            d1[1] = (uint32_t)f2bf(c.z * LOG2E) | ((uint32_t)f2bf(c.w * LOG2E) << 16);
        }
        __syncthreads();
        cur ^= 1;
    }

    // row-sum reduction across the 16 l15 lanes (stays within quad group)
    #pragma unroll
    for (int r = 0; r < 4; ++r) {
        #pragma unroll
        for (int off = 1; off < 16; off <<= 1)
            l_r[r] += __shfl_xor(l_r[r], off, 64);
    }

    // epilogue: normalize, write bf16 to ao[b][i][h*32+d]
    unsigned short* aop = ao + ((size_t)b * NN + i0) * HID + h * DH;
    #pragma unroll
    for (int r = 0; r < 4; ++r) {
        const int row = quad * 4 + r;
        const float inv = 1.0f / l_r[r];
        aop[(size_t)row * HID + l15]      = f2bf(oa0[r] * inv);
        aop[(size_t)row * HID + 16 + l15] = f2bf(oa1[r] * inv);
    }
}

// ---------------------------------------------------------------------------
// K3: out projection, bf16 MFMA.
// out[b][o][n] = sum_c w_out[o][c] * ao[b][n][c] + b_out[o]
// ---------------------------------------------------------------------------
__global__ __launch_bounds__(256) void out_proj(const unsigned short* __restrict__ wob,
                                                const unsigned short* __restrict__ aob,
                                                const float* __restrict__ bout,
                                                float* __restrict__ out) {
    const int n0 = blockIdx.x * 64;
    const int o0 = blockIdx.y * 64;
    const int b  = blockIdx.z;
    const int t = threadIdx.x;
    const int w = t >> 6, lane = t & 63, l15 = lane & 15, quad = lane >> 4;
    const int orow = o0 + w * 16;

    float4v acc[4] = {{0.f,0.f,0.f,0.f},{0.f,0.f,0.f,0.f},
                      {0.f,0.f,0.f,0.f},{0.f,0.f,0.f,0.f}};
    const unsigned short* ap = aob + ((size_t)b * NN + n0) * HID;
    #pragma unroll
    for (int c0 = 0; c0 < HID; c0 += 32) {
        short8 af = *(const short8*)(wob + (size_t)(orow + l15) * HID + c0 + quad * 8);
        #pragma unroll
        for (int jj = 0; jj < 4; ++jj) {
            short8 bf = *(const short8*)(ap + (size_t)(jj * 16 + l15) * HID + c0 + quad * 8);
            acc[jj] = __builtin_amdgcn_mfma_f32_16x16x32_bf16(af, bf, acc[jj], 0, 0, 0);
        }
    }
    float* op = out + (size_t)b * HID * NN;
    #pragma unroll
    for (int r = 0; r < 4; ++r) {
        const int o = orow + quad * 4 + r;
        const float bv = bout[o];
        #pragma unroll
        for (int jj = 0; jj < 4; ++jj)
            op[(size_t)o * NN + n0 + jj * 16 + l15] = acc[jj][r] + bv;
    }
}

// ---------------------------------------------------------------------------
extern "C" void kernel_launch(void* const* d_in, const int* in_sizes, int n_in,
                              void* d_out, int out_size, void* d_ws, size_t ws_size,
                              hipStream_t stream) {
    const float* x        = (const float*)d_in[0];  // [4][256][2304]
    const float* pos_bias = (const float*)d_in[1];  // [8][2304][2304]
    const float* w_qkv    = (const float*)d_in[2];  // [768][256]
    const float* w_out    = (const float*)d_in[3];  // [256][256]
    const float* b_out    = (const float*)d_in[4];  // [256]
    float* out = (float*)d_out;                     // [4][256][2304]

    // workspace carve-up (256B-aligned); total ~24.5 MB (proven-safe size)
    char* ws = (char*)d_ws;
    unsigned short* q   = (unsigned short*)(ws);                      //  4,718,592
    unsigned short* k   = (unsigned short*)(ws + 4718592);            //  4,718,592
    unsigned short* v   = (unsigned short*)(ws + 9437184);            //  4,718,592
    unsigned short* ao  = (unsigned short*)(ws + 14155776);           //  4,718,592
    unsigned short* wob = (unsigned short*)(ws + 18874368);           //    131,072
    unsigned short* whi = (unsigned short*)(ws + 19005440);           //    393,216
    unsigned short* wlo = (unsigned short*)(ws + 19398656);           //    393,216
    unsigned short* xT  = (unsigned short*)(ws + 19791872);           //  4,718,592

    prep_kernel<<<3072, 256, 0, stream>>>(x, w_qkv, w_out, xT, whi, wlo, wob);
    qkv_gemm_bf16<<<dim3(12, NN / 64, BB), 256, 0, stream>>>(xT, whi, wlo, q, k, v);
    attn_kernel<<<dim3(NN / 16, NH), 256, 0, stream>>>(q, k, v, pos_bias, ao);
    out_proj<<<dim3(NN / 64, HID / 64, BB), 256, 0, stream>>>(wob, ao, b_out, out);
}

// Round 4
// 430.544 us; speedup vs baseline: 1.0763x; 1.0014x over previous
//
#include <hip/hip_runtime.h>
#include <stdint.h>
#include <stddef.h>

// Problem constants
#define BB 4
#define CC 256
#define NH 8
#define DH 32
#define NN 2304      // 48*48
#define O3 768
#define HID 256
#define QK_SCALE 0.17677669529663687f  // 32^-0.5
#define LOG2E 1.44269504f

typedef __attribute__((ext_vector_type(8))) short short8;
typedef __attribute__((ext_vector_type(4))) float float4v;

__device__ __forceinline__ unsigned short f2bf(float f) {
    union { float f; uint32_t u; } v; v.f = f;
    uint32_t u = v.u;
    return (unsigned short)((u + 0x7FFFu + ((u >> 16) & 1u)) >> 16);   // RNE
}
__device__ __forceinline__ float bf2f(unsigned short s) {
    union { uint32_t u; float f; } v; v.u = ((uint32_t)s) << 16;
    return v.f;
}

// ---------------------------------------------------------------------------
// K0: prep = transpose-cast x -> xT bf16  (blocks 0..2303)
//          + cast w_qkv hi/lo, w_out      (blocks 2304..3071)
// ---------------------------------------------------------------------------
__global__ __launch_bounds__(256) void prep_kernel(const float* __restrict__ x,
                                                   const float* __restrict__ wqkv,
                                                   const float* __restrict__ wout,
                                                   unsigned short* __restrict__ xT,
                                                   unsigned short* __restrict__ whi,
                                                   unsigned short* __restrict__ wlo,
                                                   unsigned short* __restrict__ wob) {
    const int bid = blockIdx.x;
    const int t = threadIdx.x;
    if (bid < 2304) {      // transpose 32x32 tile of x
        const int n0 = (bid % 72) * 32, c0 = ((bid / 72) % 8) * 32, b = bid / 576;
        __shared__ float ls[32][33];
        {
            int c = t >> 3, nc = (t & 7) * 4;
            float4 v4 = *(const float4*)(x + ((size_t)b * CC + c0 + c) * NN + n0 + nc);
            ls[c][nc] = v4.x; ls[c][nc + 1] = v4.y; ls[c][nc + 2] = v4.z; ls[c][nc + 3] = v4.w;
        }
        __syncthreads();
        {
            int n = t >> 3, cl = (t & 7) * 4;
            uint32_t p0 = (uint32_t)f2bf(ls[cl + 0][n]) | ((uint32_t)f2bf(ls[cl + 1][n]) << 16);
            uint32_t p1 = (uint32_t)f2bf(ls[cl + 2][n]) | ((uint32_t)f2bf(ls[cl + 3][n]) << 16);
            uint32_t* dst = (uint32_t*)(xT + ((size_t)b * NN + n0 + n) * CC + c0 + cl);
            dst[0] = p0; dst[1] = p1;
        }
    } else {               // weight casts
        int i = (bid - 2304) * 256 + t;
        float wv = wqkv[i];
        unsigned short hi = f2bf(wv);
        whi[i] = hi;
        wlo[i] = f2bf(wv - bf2f(hi));
        if (i < HID * HID) wob[i] = f2bf(wout[i]);
    }
}

// ---------------------------------------------------------------------------
// K1: fused QKV projection, bf16 MFMA, writes q/k/v directly in final layouts.
//   q,k bf16 [b][h][n][32] (q scaled by QK_SCALE*LOG2E), v bf16 [b][h][32][n]
// ---------------------------------------------------------------------------
__global__ __launch_bounds__(256) void qkv_gemm_bf16(const unsigned short* __restrict__ xT,
                                                     const unsigned short* __restrict__ whi,
                                                     const unsigned short* __restrict__ wlo,
                                                     unsigned short* __restrict__ q,
                                                     unsigned short* __restrict__ k,
                                                     unsigned short* __restrict__ v) {
    const int og = blockIdx.x;
    const int n0 = blockIdx.y * 64;
    const int b  = blockIdx.z;
    const int t = threadIdx.x;
    const int w = t >> 6, lane = t & 63, l15 = lane & 15, quad = lane >> 4;
    const unsigned short* xb = xT + (size_t)b * NN * CC;

    float4v acc[4] = {{0.f,0.f,0.f,0.f},{0.f,0.f,0.f,0.f},
                      {0.f,0.f,0.f,0.f},{0.f,0.f,0.f,0.f}};

    if (og < 8) {   // ---- qk mode: A = xT rows n, B = w rows o ----
        const int o0 = og * 64;
        const unsigned short* ap = xb + (size_t)(n0 + w * 16 + l15) * CC + quad * 8;
        #pragma unroll
        for (int c0 = 0; c0 < CC; c0 += 32) {
            short8 af = *(const short8*)(ap + c0);
            #pragma unroll
            for (int jj = 0; jj < 4; ++jj) {
                const size_t wo = (size_t)(o0 + jj * 16 + l15) * CC + c0 + quad * 8;
                short8 bh = *(const short8*)(whi + wo);
                short8 bl = *(const short8*)(wlo + wo);
                acc[jj] = __builtin_amdgcn_mfma_f32_16x16x32_bf16(af, bh, acc[jj], 0, 0, 0);
                acc[jj] = __builtin_amdgcn_mfma_f32_16x16x32_bf16(af, bl, acc[jj], 0, 0, 0);
            }
        }
        #pragma unroll
        for (int jj = 0; jj < 4; ++jj) {
            const int o = o0 + jj * 16 + l15;
            const int which = o >> 8;            // 0=q 1=k
            const int h = (o >> 5) & 7, d = o & 31;
            unsigned short* dst = which ? k : q;
            const float sc = which ? 1.0f : QK_SCALE * LOG2E;
            #pragma unroll
            for (int r = 0; r < 4; ++r) {
                const int n = n0 + w * 16 + quad * 4 + r;
                dst[(((size_t)b * NH + h) * NN + n) * DH + d] = f2bf(acc[jj][r] * sc);
            }
        }
    } else {        // ---- v mode: A = w rows o, B = xT rows n ----
        const int o0 = 512 + (og - 8) * 64;
        const size_t wr = (size_t)(o0 + w * 16 + l15) * CC + quad * 8;
        #pragma unroll
        for (int c0 = 0; c0 < CC; c0 += 32) {
            short8 ah = *(const short8*)(whi + wr + c0);
            short8 al = *(const short8*)(wlo + wr + c0);
            #pragma unroll
            for (int jj = 0; jj < 4; ++jj) {
                short8 bf = *(const short8*)(xb + (size_t)(n0 + jj * 16 + l15) * CC + c0 + quad * 8);
                acc[jj] = __builtin_amdgcn_mfma_f32_16x16x32_bf16(ah, bf, acc[jj], 0, 0, 0);
                acc[jj] = __builtin_amdgcn_mfma_f32_16x16x32_bf16(al, bf, acc[jj], 0, 0, 0);
            }
        }
        #pragma unroll
        for (int r = 0; r < 4; ++r) {
            const int o = o0 + w * 16 + quad * 4 + r;
            const int h = (o >> 5) & 7, d = o & 31;
            #pragma unroll
            for (int jj = 0; jj < 4; ++jj) {
                const int n = n0 + jj * 16 + l15;
                v[(((size_t)b * NH + h) * DH + d) * NN + n] = f2bf(acc[jj][r]);
            }
        }
    }
}

// ---------------------------------------------------------------------------
// K2: fused attention, batch-fused (4 waves = 4 batches share one (h,i-tile)).
// v3 changes vs v2 (all latency/VALU, math identical):
//  - K register double-buffer: next tile's 8 K fragments prefetched a full
//    iteration ahead (hand-written 2-phase loop, static reg indices).
//  - V loads issued at top of iteration, consumed ~500cy later at PV.
//  - bias staged in LDS as fp32 in MFMA C-fragment layout [64][36] and fed
//    as the QK MFMA C-input (zero VALU for bias; 8 ds_read_b128 per iter).
//  - P->bf16 via v_cvt_pk_bf16_f32 (RNE, same values as manual f2bf).
// Wave-private ps (no barrier needed around it); one barrier per iteration
// for the shared bias double-buffer (write-late pattern).
// grid (NN/16, NH), block 256.
// ---------------------------------------------------------------------------
__device__ __forceinline__ void bias_store(float (*bc)[36], int qr, int kc, float4 v) {
    // scatter 4 consecutive cols (kc..kc+3) of tile-row qr into C-frag layout:
    // bias_c[(q'>>2)*16 + (k'&15)][(k'>>4)*4 + (q'&3)]
    const int Lb = (qr >> 2) * 16;
    const int iq = qr & 3;
    const int kh = (kc >> 4) * 4 + iq;
    const int kl = kc & 15;          // in {0,4,8,12}; kl+3 <= 15, no wrap
    bc[Lb + kl + 0][kh] = v.x * LOG2E;
    bc[Lb + kl + 1][kh] = v.y * LOG2E;
    bc[Lb + kl + 2][kh] = v.z * LOG2E;
    bc[Lb + kl + 3][kh] = v.w * LOG2E;
}

__global__ __launch_bounds__(256) void attn_kernel(const unsigned short* __restrict__ qg,
                                                   const unsigned short* __restrict__ kg,
                                                   const unsigned short* __restrict__ vg,
                                                   const float* __restrict__ bias,
                                                   unsigned short* __restrict__ ao) {
    const int i0   = blockIdx.x * 16;
    const int h    = blockIdx.y;
    const int t    = threadIdx.x;
    const int b    = t >> 6;            // wave index = batch index (BB==4)
    const int lane = t & 63;
    const int l15  = lane & 15;
    const int quad = lane >> 4;

    __shared__ __align__(16) float bias_c[2][64][36];         // 18.4 KB fp32 C-frag dbuf
    __shared__ __align__(16) unsigned short ps[BB][16][136];  // 17.4 KB per-wave P

    const size_t bh = (size_t)b * NH + h;
    const unsigned short* qp = qg + bh * NN * DH;
    const unsigned short* kp = kg + bh * NN * DH;
    const unsigned short* vp = vg + bh * DH * NN;

    short8 qf = *(const short8*)(qp + (size_t)(i0 + l15) * DH + quad * 8);

    float4v oa0 = {0.f, 0.f, 0.f, 0.f};
    float4v oa1 = {0.f, 0.f, 0.f, 0.f};
    float l_r[4] = {0.f, 0.f, 0.f, 0.f};

    // bias staging map: thread t covers tile-rows {t>>5, (t>>5)+8},
    // cols (t&31)*4 .. +3 (coalesced float4 global loads)
    const float* bsrc = bias + ((size_t)h * NN + i0) * NN;
    const int srow = t >> 5;
    const int scol = (t & 31) * 4;

    // prologue: stage bias tile 0 (fp32 C-layout) + load K tile 0
    {
        float4 a = *(const float4*)(bsrc + (size_t)srow * NN + scol);
        float4 c = *(const float4*)(bsrc + (size_t)(srow + 8) * NN + scol);
        bias_store(bias_c[0], srow, scol, a);
        bias_store(bias_c[0], srow + 8, scol, c);
    }
    short8 ka[8], kb[8];
    #pragma unroll
    for (int jj = 0; jj < 8; ++jj)
        ka[jj] = *(const short8*)(kp + (size_t)(jj * 16 + l15) * DH + quad * 8);
    __syncthreads();

#define ATTN_PHASE(KC, KN, JT, PJT, HAVEP, CUR, NXT)                               \
{                                                                                  \
    /* V for THIS tile - issued first, needed last (PV) */                         \
    short8 vv[8];                                                                  \
    _Pragma("unroll")                                                              \
    for (int cc = 0; cc < 4; ++cc) {                                               \
        vv[2*cc]   = *(const short8*)(vp + (size_t)l15 * NN + (JT) + cc*32 + quad*8);        \
        vv[2*cc+1] = *(const short8*)(vp + (size_t)(l15+16) * NN + (JT) + cc*32 + quad*8);   \
    }                                                                              \
    /* K prefetch for NEXT tile (consumed next iteration) */                       \
    if (HAVEP) {                                                                   \
        _Pragma("unroll")                                                          \
        for (int jj = 0; jj < 8; ++jj)                                             \
            KN[jj] = *(const short8*)(kp + (size_t)((PJT) + jj*16 + l15) * DH + quad*8);     \
    }                                                                              \
    /* bias global loads for NEXT tile (write-late below) */                       \
    float4 bga, bgc;                                                               \
    if (HAVEP) {                                                                   \
        bga = *(const float4*)(bsrc + (size_t)srow * NN + (PJT) + scol);           \
        bgc = *(const float4*)(bsrc + (size_t)(srow + 8) * NN + (PJT) + scol);     \
    }                                                                              \
    /* S = Q K^T with bias as C-init (q pre-scaled by SCALE*LOG2E) */              \
    float4v s[8];                                                                  \
    _Pragma("unroll")                                                              \
    for (int jj = 0; jj < 8; ++jj) {                                               \
        float4v bfr = *(const float4v*)&bias_c[CUR][quad * 16 + l15][jj * 4];      \
        s[jj] = __builtin_amdgcn_mfma_f32_16x16x32_bf16(qf, KC[jj], bfr, 0, 0, 0); \
    }                                                                              \
    /* p = exp2(s); pack pairs to bf16 via cvt_pk (RNE); row partial sums */       \
    _Pragma("unroll")                                                              \
    for (int r = 0; r < 4; ++r) {                                                  \
        const int row = quad * 4 + r;                                              \
        float pv_[8];                                                              \
        _Pragma("unroll")                                                          \
        for (int jj = 0; jj < 8; ++jj) { pv_[jj] = exp2f(s[jj][r]); l_r[r] += pv_[jj]; }     \
        _Pragma("unroll")                                                          \
        for (int jp = 0; jp < 4; ++jp) {                                           \
            uint32_t pk;                                                           \
            asm("v_cvt_pk_bf16_f32 %0, %1, %2" : "=v"(pk) : "v"(pv_[2*jp]), "v"(pv_[2*jp+1])); \
            ps[b][row][(2*jp) * 16 + l15]     = (unsigned short)pk;                \
            ps[b][row][(2*jp+1) * 16 + l15]   = (unsigned short)(pk >> 16);        \
        }                                                                          \
    }                                                                              \
    /* O += P x V (ps wave-private: same-wave DS ordering, no barrier) */          \
    _Pragma("unroll")                                                              \
    for (int cc = 0; cc < 4; ++cc) {                                               \
        short8 pa = *(const short8*)&ps[b][l15][cc * 32 + quad * 8];               \
        oa0 = __builtin_amdgcn_mfma_f32_16x16x32_bf16(pa, vv[2*cc],   oa0, 0, 0, 0);         \
        oa1 = __builtin_amdgcn_mfma_f32_16x16x32_bf16(pa, vv[2*cc+1], oa1, 0, 0, 0);         \
    }                                                                              \
    /* write-late: next bias tile into the other buffer, then the barrier */       \
    if (HAVEP) {                                                                   \
        bias_store(bias_c[NXT], srow, scol, bga);                                  \
        bias_store(bias_c[NXT], srow + 8, scol, bgc);                              \
    }                                                                              \
    __syncthreads();                                                               \
}

    for (int jt0 = 0; jt0 < NN; jt0 += 256) {        // 9 outer iters x 2 tiles
        ATTN_PHASE(ka, kb, jt0,       jt0 + 128, true,               0, 1)
        ATTN_PHASE(kb, ka, jt0 + 128, jt0 + 256, (jt0 + 256 < NN),   1, 0)
    }
#undef ATTN_PHASE

    // row-sum reduction across the 16 l15 lanes (stays within quad group)
    #pragma unroll
    for (int r = 0; r < 4; ++r) {
        #pragma unroll
        for (int off = 1; off < 16; off <<= 1)
            l_r[r] += __shfl_xor(l_r[r], off, 64);
    }

    // epilogue: normalize, write bf16 to ao[b][i][h*32+d]
    unsigned short* aop = ao + ((size_t)b * NN + i0) * HID + h * DH;
    #pragma unroll
    for (int r = 0; r < 4; ++r) {
        const int row = quad * 4 + r;
        const float inv = 1.0f / l_r[r];
        aop[(size_t)row * HID + l15]      = f2bf(oa0[r] * inv);
        aop[(size_t)row * HID + 16 + l15] = f2bf(oa1[r] * inv);
    }
}

// ---------------------------------------------------------------------------
// K3: out projection, bf16 MFMA.
// out[b][o][n] = sum_c w_out[o][c] * ao[b][n][c] + b_out[o]
// ---------------------------------------------------------------------------
__global__ __launch_bounds__(256) void out_proj(const unsigned short* __restrict__ wob,
                                                const unsigned short* __restrict__ aob,
                                                const float* __restrict__ bout,
                                                float* __restrict__ out) {
    const int n0 = blockIdx.x * 64;
    const int o0 = blockIdx.y * 64;
    const int b  = blockIdx.z;
    const int t = threadIdx.x;
    const int w = t >> 6, lane = t & 63, l15 = lane & 15, quad = lane >> 4;
    const int orow = o0 + w * 16;

    float4v acc[4] = {{0.f,0.f,0.f,0.f},{0.f,0.f,0.f,0.f},
                      {0.f,0.f,0.f,0.f},{0.f,0.f,0.f,0.f}};
    const unsigned short* ap = aob + ((size_t)b * NN + n0) * HID;
    #pragma unroll
    for (int c0 = 0; c0 < HID; c0 += 32) {
        short8 af = *(const short8*)(wob + (size_t)(orow + l15) * HID + c0 + quad * 8);
        #pragma unroll
        for (int jj = 0; jj < 4; ++jj) {
            short8 bf = *(const short8*)(ap + (size_t)(jj * 16 + l15) * HID + c0 + quad * 8);
            acc[jj] = __builtin_amdgcn_mfma_f32_16x16x32_bf16(af, bf, acc[jj], 0, 0, 0);
        }
    }
    float* op = out + (size_t)b * HID * NN;
    #pragma unroll
    for (int r = 0; r < 4; ++r) {
        const int o = orow + quad * 4 + r;
        const float bv = bout[o];
        #pragma unroll
        for (int jj = 0; jj < 4; ++jj)
            op[(size_t)o * NN + n0 + jj * 16 + l15] = acc[jj][r] + bv;
    }
}

// ---------------------------------------------------------------------------
extern "C" void kernel_launch(void* const* d_in, const int* in_sizes, int n_in,
                              void* d_out, int out_size, void* d_ws, size_t ws_size,
                              hipStream_t stream) {
    const float* x        = (const float*)d_in[0];  // [4][256][2304]
    const float* pos_bias = (const float*)d_in[1];  // [8][2304][2304]
    const float* w_qkv    = (const float*)d_in[2];  // [768][256]
    const float* w_out    = (const float*)d_in[3];  // [256][256]
    const float* b_out    = (const float*)d_in[4];  // [256]
    float* out = (float*)d_out;                     // [4][256][2304]

    // workspace carve-up (256B-aligned); total ~24.5 MB (proven-safe size)
    char* ws = (char*)d_ws;
    unsigned short* q   = (unsigned short*)(ws);                      //  4,718,592
    unsigned short* k   = (unsigned short*)(ws + 4718592);            //  4,718,592
    unsigned short* v   = (unsigned short*)(ws + 9437184);            //  4,718,592
    unsigned short* ao  = (unsigned short*)(ws + 14155776);           //  4,718,592
    unsigned short* wob = (unsigned short*)(ws + 18874368);           //    131,072
    unsigned short* whi = (unsigned short*)(ws + 19005440);           //    393,216
    unsigned short* wlo = (unsigned short*)(ws + 19398656);           //    393,216
    unsigned short* xT  = (unsigned short*)(ws + 19791872);           //  4,718,592

    prep_kernel<<<3072, 256, 0, stream>>>(x, w_qkv, w_out, xT, whi, wlo, wob);
    qkv_gemm_bf16<<<dim3(12, NN / 64, BB), 256, 0, stream>>>(xT, whi, wlo, q, k, v);
    attn_kernel<<<dim3(NN / 16, NH), 256, 0, stream>>>(q, k, v, pos_bias, ao);
    out_proj<<<dim3(NN / 64, HID / 64, BB), 256, 0, stream>>>(wob, ao, b_out, out);
}